// Round 3
// baseline (1018.087 us; speedup 1.0000x reference)
//
#include <hip/hip_runtime.h>
#include <hip/hip_bf16.h>

#define N_TOK   8192
#define DM      1024     // d_model
#define DH      16384    // d_hidden
#define KTOP    32
#define NCAND   512      // candidate buffer per row (packed u32)
#define CAND_T  2.2f     // fixed candidate threshold (see stats in journal)
#define DZONE   0.10f    // zone half-width >= 2*delta (delta ~= 0.038)

typedef unsigned int uint;
typedef __attribute__((ext_vector_type(8))) short bf16x8;
typedef __attribute__((ext_vector_type(4))) float f32x4;

__device__ inline ushort f2bf(float f) {
    uint u = __float_as_uint(f);
    uint r = (u + 0x7FFFu + ((u >> 16) & 1u)) >> 16;
    return (ushort)r;
}
__device__ inline float bf2f(ushort u) {
    return __uint_as_float(((uint)u) << 16);
}

__device__ inline void load_lds16(const void* g, void* l) {
    __builtin_amdgcn_global_load_lds(
        (const __attribute__((address_space(1))) void*)g,
        (__attribute__((address_space(3))) void*)l, 16, 0, 0);
}

// ---------------------------------------------------------------------------
// Convert x -> bf16(x - b_pre)   [N_TOK, DM]
// ---------------------------------------------------------------------------
__global__ __launch_bounds__(256) void conv_x(
    const float* __restrict__ x, const float* __restrict__ b_pre,
    ushort* __restrict__ A)
{
    int i = (blockIdx.x * 256 + threadIdx.x) * 4;
    float4 v = *(const float4*)&x[i];
    float4 b = *(const float4*)&b_pre[i & (DM - 1)];
    ushort4 o;
    o.x = f2bf(v.x - b.x); o.y = f2bf(v.y - b.y);
    o.z = f2bf(v.z - b.z); o.w = f2bf(v.w - b.w);
    *(ushort4*)&A[i] = o;
}

// Convert W_enc -> bf16   [DH, DM]
__global__ __launch_bounds__(256) void conv_w(
    const float* __restrict__ W, ushort* __restrict__ B)
{
    int i = (blockIdx.x * 256 + threadIdx.x) * 4;
    float4 v = *(const float4*)&W[i];
    ushort4 o;
    o.x = f2bf(v.x); o.y = f2bf(v.y); o.z = f2bf(v.z); o.w = f2bf(v.w);
    *(ushort4*)&B[i] = o;
}

// ---------------------------------------------------------------------------
// bf16 MFMA GEMM (m97 structure) + fused candidate extraction.
// pre[n][h] = A[n][:] . B[h][:] + b_act[h]; push (n,h,val) when val > CAND_T.
// Candidate pack: (bf16(val)<<16) | (16383 - h)  -> u32 compare == rank order
// (val desc, idx asc tiebreak).
// ---------------------------------------------------------------------------
__global__ __launch_bounds__(256, 3) void gemm_bf16(
    const ushort* __restrict__ A, const ushort* __restrict__ B,
    const float* __restrict__ b_act, float* __restrict__ pre,
    uint* __restrict__ cand, int* __restrict__ ccnt)
{
    __shared__ ushort As[128 * 64];   // 16 KB
    __shared__ ushort Bs[128 * 64];   // 16 KB

    const int tid  = threadIdx.x;
    const int wid  = tid >> 6;
    const int lane = tid & 63;
    const int wr   = wid >> 1;        // wave row 0..1
    const int wc   = wid & 1;         // wave col 0..1

    // XCD-aware bijective swizzle (8192 % 8 == 0), bn-major for L2 B reuse
    int swz = (blockIdx.x & 7) * 1024 + (blockIdx.x >> 3);
    const int bm = swz & 63;          // 64 row tiles
    const int bn = swz >> 6;          // 128 col tiles
    const int row0 = bm * 128;
    const int col0 = bn * 128;

    f32x4 acc[4][4] = {};

    const int chunk = wid * 64 + lane;
    for (int k0 = 0; k0 < DM; k0 += 64) {
        #pragma unroll
        for (int i = 0; i < 4; ++i) {
            int ch = i * 256 + chunk;
            int r  = ch >> 3;
            int c8 = (ch & 7) * 8;
            load_lds16(&A[(size_t)(row0 + r) * DM + k0 + c8],
                       &As[(size_t)(i * 256 + wid * 64) * 8]);
            load_lds16(&B[(size_t)(col0 + r) * DM + k0 + c8],
                       &Bs[(size_t)(i * 256 + wid * 64) * 8]);
        }
        __syncthreads();
        #pragma unroll
        for (int ks = 0; ks < 2; ++ks) {
            const int kb = ks * 32 + (lane >> 4) * 8;
            bf16x8 af[4], bfr[4];
            #pragma unroll
            for (int m = 0; m < 4; ++m)
                af[m] = *(const bf16x8*)&As[(wr * 64 + m * 16 + (lane & 15)) * 64 + kb];
            #pragma unroll
            for (int n = 0; n < 4; ++n)
                bfr[n] = *(const bf16x8*)&Bs[(wc * 64 + n * 16 + (lane & 15)) * 64 + kb];
            #pragma unroll
            for (int m = 0; m < 4; ++m)
                #pragma unroll
                for (int n = 0; n < 4; ++n)
                    acc[m][n] = __builtin_amdgcn_mfma_f32_16x16x32_bf16(
                        af[m], bfr[n], acc[m][n], 0, 0, 0);
        }
        __syncthreads();
    }

    // epilogue: C row = (lane>>4)*4 + r within frag, col = lane&15
    const int ccol = col0 + wc * 64 + (lane & 15);
    float ba[4];
    #pragma unroll
    for (int n = 0; n < 4; ++n) ba[n] = b_act[ccol + n * 16];
    #pragma unroll
    for (int m = 0; m < 4; ++m) {
        const int crow = row0 + wr * 64 + m * 16 + (lane >> 4) * 4;
        #pragma unroll
        for (int r = 0; r < 4; ++r) {
            #pragma unroll
            for (int n = 0; n < 4; ++n) {
                float o = acc[m][n][r] + ba[n];
                int rr = crow + r;
                int cc = ccol + n * 16;
                pre[(size_t)rr * DH + cc] = o;
                if (o > CAND_T) {
                    int p = atomicAdd(&ccnt[rr], 1);
                    if (p < NCAND)
                        cand[(size_t)rr * NCAND + p] =
                            ((uint)f2bf(o) << 16) | (uint)(16383 - cc);
                }
            }
        }
    }
}

// ---------------------------------------------------------------------------
// Exact top-32 from candidate list (no sort):
//   rank-by-count on packed u32; a32 = rank-31 value; certain-in above
//   a32+DZ keep approx; zone [a32-DZ, a32+DZ] recomputed exactly (f32 wave
//   dots); zone re-ranked by exact; winners scatter into sparse + vals/inds.
// Also zeroes the sparse row.
// ---------------------------------------------------------------------------
__global__ __launch_bounds__(512) void fix_topk(
    const float* __restrict__ x, const float* __restrict__ b_pre,
    const float* __restrict__ W, const float* __restrict__ b_act,
    const uint* __restrict__ cand, const int* __restrict__ ccnt,
    float* __restrict__ sparse, float* __restrict__ vals, int* __restrict__ inds)
{
    const int row = blockIdx.x;
    const int tid = threadIdx.x;
    const int wid = tid >> 6, lane = tid & 63;

    // zero sparse row (4096 float4)
    float4 z4 = {0.f, 0.f, 0.f, 0.f};
    float4* srow = (float4*)(sparse + (size_t)row * DH);
    #pragma unroll
    for (int i = 0; i < 8; ++i) srow[tid + i * 512] = z4;

    __shared__ float xs[DM];
    for (int i = tid; i < DM; i += 512)
        xs[i] = x[(size_t)row * DM + i] - b_pre[i];

    const int n = min(ccnt[row], NCAND);

    __shared__ uint  spk[NCAND];
    __shared__ float sex[NCAND];   // approx, later exact for zone
    __shared__ int   sid[NCAND];
    __shared__ short zf[NCAND];
    __shared__ int   zlist[NCAND];
    __shared__ float sa32;
    __shared__ int   scin, zn;

    uint pk = (tid < n) ? cand[(size_t)row * NCAND + tid] : 0u;
    spk[tid] = pk;
    sex[tid] = bf2f((ushort)(pk >> 16));
    sid[tid] = (tid < n) ? (int)(16383u - (pk & 0xFFFFu)) : -1;
    if (tid == 0) { scin = 0; zn = 0; }
    // pre-init output slots (degenerate-row insurance)
    if (tid < KTOP) {
        vals[(size_t)row * KTOP + tid] = 0.f;
        inds[(size_t)row * KTOP + tid] = -1;
    }
    __syncthreads();

    // rank by count (packed compare = val desc, idx asc)
    int rank = 0;
    for (int j = 0; j < NCAND; ++j)
        rank += (spk[j] > pk);
    if (rank == 31) sa32 = sex[tid];
    __syncthreads();

    const float a32 = sa32;
    const float myv = sex[tid];
    const bool cin  = (myv > a32 + DZONE);
    const bool zone = !cin && (myv >= a32 - DZONE) && (tid < n);

    unsigned long long bal = __ballot(cin);
    if (lane == 0) atomicAdd(&scin, __popcll(bal));
    if (zone) { int p = atomicAdd(&zn, 1); zlist[p] = tid; }
    zf[tid] = zone ? 1 : 0;
    __syncthreads();

    const int cin_total = scin;
    const int znum = zn;

    // exact f32 recompute of zone members, one per wave
    for (int m = wid; m < znum; m += 8) {
        int t = zlist[m];
        int h = sid[t];
        if (h >= 0) {
            const float* wrow = W + (size_t)h * DM;
            float s = 0.f;
            #pragma unroll
            for (int c = 0; c < 16; ++c)
                s = fmaf(xs[lane + c * 64], wrow[lane + c * 64], s);
            #pragma unroll
            for (int off = 32; off; off >>= 1) s += __shfl_down(s, off);
            if (lane == 0) sex[t] = s + b_act[h];
        }
    }
    __syncthreads();

    // certain-in: slot = rank (ranks 0..cin_total-1 are exactly the cin set)
    int slot = -1;
    float outv = 0.f;
    if (cin) { slot = rank; outv = myv; }
    else if (zone) {
        float ev = sex[tid];
        int   mi = sid[tid];
        int zrank = 0;
        for (int j = 0; j < NCAND; ++j) {
            if (zf[j]) {
                float ov = sex[j];
                zrank += (ov > ev) || (ov == ev && sid[j] < mi);
            }
        }
        if (zrank < KTOP - cin_total) { slot = cin_total + zrank; outv = ev; }
    }
    __syncthreads();
    if (slot >= 0 && slot < KTOP) {
        int h = sid[tid];
        float r = fmaxf(outv, 0.f);
        vals[(size_t)row * KTOP + slot] = r;
        inds[(size_t)row * KTOP + slot] = h;
        if (h >= 0) sparse[(size_t)row * DH + h] = r;
    }
}

// ---------------------------------------------------------------------------
// Transpose W_dec [DM, DH] f32 -> W_dec^T [DH, DM] bf16
// ---------------------------------------------------------------------------
__global__ __launch_bounds__(256) void transpose_dec(
    const float* __restrict__ W, ushort* __restrict__ WT)
{
    __shared__ float t[32][33];
    const int tx = threadIdx.x;   // 0..31
    const int ty = threadIdx.y;   // 0..7
    const int h0 = blockIdx.x * 32;
    const int d0 = blockIdx.y * 32;
    #pragma unroll
    for (int r = 0; r < 4; ++r)
        t[ty + r * 8][tx] = W[(size_t)(d0 + ty + r * 8) * DH + h0 + tx];
    __syncthreads();
    #pragma unroll
    for (int r = 0; r < 4; ++r)
        WT[(size_t)(h0 + ty + r * 8) * DM + d0 + tx] = f2bf(t[tx][ty + r * 8]);
}

// ---------------------------------------------------------------------------
// Decode: recon[n][d] = sum_j vals[n][j] * WdecT[inds[n][j]][d] + b_pre[d]
// ---------------------------------------------------------------------------
__global__ __launch_bounds__(256) void recon_kernel(
    const float* __restrict__ vals, const int* __restrict__ inds,
    const ushort* __restrict__ wdecT, const float* __restrict__ b_pre,
    float* __restrict__ recon)
{
    const int row = blockIdx.x;
    const int tid = threadIdx.x;
    __shared__ float lval[KTOP];
    __shared__ int   lind[KTOP];
    if (tid < KTOP) {
        lval[tid] = vals[(size_t)row * KTOP + tid];
        lind[tid] = inds[(size_t)row * KTOP + tid];
    }
    __syncthreads();

    const int d = tid * 4;
    float4 a = *(const float4*)&b_pre[d];
    #pragma unroll 8
    for (int j = 0; j < KTOP; ++j) {
        float vj = lval[j];
        int h = lind[j];
        if (vj != 0.f && h >= 0) {
            ushort4 w = *(const ushort4*)&wdecT[(size_t)h * DM + d];
            a.x = fmaf(vj, bf2f(w.x), a.x);
            a.y = fmaf(vj, bf2f(w.y), a.y);
            a.z = fmaf(vj, bf2f(w.z), a.z);
            a.w = fmaf(vj, bf2f(w.w), a.w);
        }
    }
    *(float4*)&recon[(size_t)row * DM + d] = a;
}

// ---------------------------------------------------------------------------
extern "C" void kernel_launch(void* const* d_in, const int* in_sizes, int n_in,
                              void* d_out, int out_size, void* d_ws, size_t ws_size,
                              hipStream_t stream)
{
    const float* x     = (const float*)d_in[0];
    const float* W_enc = (const float*)d_in[1];
    const float* W_dec = (const float*)d_in[2];
    const float* b_pre = (const float*)d_in[3];
    const float* b_act = (const float*)d_in[4];

    float* recon  = (float*)d_out;                       // [N, DM]
    float* sparse = recon + (size_t)N_TOK * DM;          // [N, DH]
    float* pre    = sparse + (size_t)N_TOK * DH;         // [N, DH]

    // bf16 staging of A/B inside the sparse output region (zeroed later by
    // fix_topk, which runs after gemm has consumed them)
    ushort* Abf = (ushort*)sparse;                       // 16.8 MB
    ushort* Bbf = Abf + (size_t)N_TOK * DM;              // 33.5 MB

    // workspace (~52.4 MB, same footprint as the proven round-2 layout)
    uint*   cand  = (uint*)d_ws;                                 // 16.78 MB
    int*    ccnt  = (int*)(cand + (size_t)N_TOK * NCAND);        // 32 KB
    float*  vals  = (float*)(ccnt + N_TOK);                      // 1.05 MB
    int*    inds  = (int*)(vals + (size_t)N_TOK * KTOP);         // 1.05 MB
    ushort* wdecT = (ushort*)(inds + (size_t)N_TOK * KTOP);      // 33.5 MB

    hipMemsetAsync(ccnt, 0, N_TOK * sizeof(int), stream);

    conv_x<<<N_TOK * DM / 1024, 256, 0, stream>>>(x, b_pre, Abf);
    conv_w<<<DH * DM / 1024, 256, 0, stream>>>(W_enc, Bbf);

    gemm_bf16<<<(N_TOK / 128) * (DH / 128), 256, 0, stream>>>(
        Abf, Bbf, b_act, pre, cand, ccnt);

    transpose_dec<<<dim3(DH / 32, DM / 32), dim3(32, 8), 0, stream>>>(W_dec, wdecT);

    fix_topk<<<N_TOK, 512, 0, stream>>>(x, b_pre, W_enc, b_act,
                                        cand, ccnt, sparse, vals, inds);

    recon_kernel<<<N_TOK, 256, 0, stream>>>(vals, inds, wdecT, b_pre, recon);
}

// Round 4
// 920.031 us; speedup vs baseline: 1.1066x; 1.1066x over previous
//
#include <hip/hip_runtime.h>
#include <hip/hip_bf16.h>

#define N_TOK   8192
#define DM      1024     // d_model
#define DH      16384    // d_hidden
#define KTOP    32
#define NCAND   256      // candidate buffer per row
#define DZ      0.08f    // zone half-width >= 2*delta (observed delta <= 0.031)

typedef unsigned int uint;
typedef __attribute__((ext_vector_type(8))) short bf16x8;
typedef __attribute__((ext_vector_type(4))) float f32x4;

__device__ inline ushort f2bf(float f) {
    uint u = __float_as_uint(f);
    uint r = (u + 0x7FFFu + ((u >> 16) & 1u)) >> 16;
    return (ushort)r;
}
__device__ inline float bf2f(ushort u) {
    return __uint_as_float(((uint)u) << 16);
}

__device__ inline void load_lds16(const void* g, void* l) {
    __builtin_amdgcn_global_load_lds(
        (const __attribute__((address_space(1))) void*)g,
        (__attribute__((address_space(3))) void*)l, 16, 0, 0);
}

// ---------------------------------------------------------------------------
// Convert x -> bf16(x - b_pre)   [N_TOK, DM]
// ---------------------------------------------------------------------------
__global__ __launch_bounds__(256) void conv_x(
    const float* __restrict__ x, const float* __restrict__ b_pre,
    ushort* __restrict__ A)
{
    int i = (blockIdx.x * 256 + threadIdx.x) * 4;
    float4 v = *(const float4*)&x[i];
    float4 b = *(const float4*)&b_pre[i & (DM - 1)];
    ushort4 o;
    o.x = f2bf(v.x - b.x); o.y = f2bf(v.y - b.y);
    o.z = f2bf(v.z - b.z); o.w = f2bf(v.w - b.w);
    *(ushort4*)&A[i] = o;
}

// Convert W_enc -> bf16   [DH, DM]
__global__ __launch_bounds__(256) void conv_w(
    const float* __restrict__ W, ushort* __restrict__ B)
{
    int i = (blockIdx.x * 256 + threadIdx.x) * 4;
    float4 v = *(const float4*)&W[i];
    ushort4 o;
    o.x = f2bf(v.x); o.y = f2bf(v.y); o.z = f2bf(v.z); o.w = f2bf(v.w);
    *(ushort4*)&B[i] = o;
}

// ---------------------------------------------------------------------------
// bf16 MFMA GEMM (m97 structure): pre[n][h] = A[n][:] . B[h][:] + b_act[h]
// (byte-identical to the measured round-2 kernel)
// ---------------------------------------------------------------------------
__global__ __launch_bounds__(256, 3) void gemm_bf16(
    const ushort* __restrict__ A, const ushort* __restrict__ B,
    const float* __restrict__ b_act, float* __restrict__ pre)
{
    __shared__ ushort As[128 * 64];   // 16 KB
    __shared__ ushort Bs[128 * 64];   // 16 KB

    const int tid  = threadIdx.x;
    const int wid  = tid >> 6;
    const int lane = tid & 63;
    const int wr   = wid >> 1;        // wave row 0..1
    const int wc   = wid & 1;         // wave col 0..1

    // XCD-aware bijective swizzle (8192 % 8 == 0), bn-major for L2 B reuse
    int swz = (blockIdx.x & 7) * 1024 + (blockIdx.x >> 3);
    const int bm = swz & 63;          // 64 row tiles
    const int bn = swz >> 6;          // 128 col tiles
    const int row0 = bm * 128;
    const int col0 = bn * 128;

    f32x4 acc[4][4] = {};

    const int chunk = wid * 64 + lane;
    for (int k0 = 0; k0 < DM; k0 += 64) {
        #pragma unroll
        for (int i = 0; i < 4; ++i) {
            int ch = i * 256 + chunk;
            int r  = ch >> 3;
            int c8 = (ch & 7) * 8;
            load_lds16(&A[(size_t)(row0 + r) * DM + k0 + c8],
                       &As[(size_t)(i * 256 + wid * 64) * 8]);
            load_lds16(&B[(size_t)(col0 + r) * DM + k0 + c8],
                       &Bs[(size_t)(i * 256 + wid * 64) * 8]);
        }
        __syncthreads();
        #pragma unroll
        for (int ks = 0; ks < 2; ++ks) {
            const int kb = ks * 32 + (lane >> 4) * 8;
            bf16x8 af[4], bfr[4];
            #pragma unroll
            for (int m = 0; m < 4; ++m)
                af[m] = *(const bf16x8*)&As[(wr * 64 + m * 16 + (lane & 15)) * 64 + kb];
            #pragma unroll
            for (int n = 0; n < 4; ++n)
                bfr[n] = *(const bf16x8*)&Bs[(wc * 64 + n * 16 + (lane & 15)) * 64 + kb];
            #pragma unroll
            for (int m = 0; m < 4; ++m)
                #pragma unroll
                for (int n = 0; n < 4; ++n)
                    acc[m][n] = __builtin_amdgcn_mfma_f32_16x16x32_bf16(
                        af[m], bfr[n], acc[m][n], 0, 0, 0);
        }
        __syncthreads();
    }

    const int ccol = col0 + wc * 64 + (lane & 15);
    float ba[4];
    #pragma unroll
    for (int n = 0; n < 4; ++n) ba[n] = b_act[ccol + n * 16];
    #pragma unroll
    for (int m = 0; m < 4; ++m) {
        const int crow = row0 + wr * 64 + m * 16 + (lane >> 4) * 4;
        #pragma unroll
        for (int r = 0; r < 4; ++r) {
            #pragma unroll
            for (int n = 0; n < 4; ++n)
                pre[(size_t)(crow + r) * DH + ccol + n * 16] = acc[m][n][r] + ba[n];
        }
    }
}

// ---------------------------------------------------------------------------
// Candidate extraction (identical to measured round-2 kernel): per row, find
// threshold t with count(>t) in [96,250] by bisection over register-cached
// values, compact candidates to ws. Also zeroes the sparse_acts row.
// ---------------------------------------------------------------------------
__global__ __launch_bounds__(512) void topk_cand(
    const float* __restrict__ pre, float* __restrict__ sparse,
    float* __restrict__ cval, int* __restrict__ cidx, int* __restrict__ ccnt)
{
    const int row = blockIdx.x;
    const int tid = threadIdx.x;
    const float* __restrict__ p = pre + (size_t)row * DH;

    float v[32];
    #pragma unroll
    for (int j = 0; j < 32; ++j) v[j] = p[j * 512 + tid];

    float4 z = {0.f, 0.f, 0.f, 0.f};
    float4* srow = (float4*)(sparse + (size_t)row * DH);
    #pragma unroll
    for (int i = 0; i < 8; ++i) srow[tid + i * 512] = z;

    __shared__ int scount;
    float lo = -30.f, hi = 30.f, t = 0.f;
    for (int it = 0; it < 20; ++it) {
        t = 0.5f * (lo + hi);
        int c = 0;
        #pragma unroll
        for (int j = 0; j < 32; ++j) c += (v[j] > t);
        #pragma unroll
        for (int off = 32; off; off >>= 1) c += __shfl_down(c, off);
        if (tid == 0) scount = 0;
        __syncthreads();
        if ((tid & 63) == 0) atomicAdd(&scount, c);
        __syncthreads();
        int total = scount;
        __syncthreads();
        if (total >= 96 && total <= 250) break;
        if (total < 96) hi = t; else lo = t;
    }

    __shared__ int wpos;
    __shared__ float scv[NCAND];
    __shared__ int   sci[NCAND];
    if (tid == 0) wpos = 0;
    __syncthreads();
    #pragma unroll
    for (int j = 0; j < 32; ++j) {
        if (v[j] > t) {
            int pz = atomicAdd(&wpos, 1);
            if (pz < NCAND) { scv[pz] = v[j]; sci[pz] = j * 512 + tid; }
        }
    }
    __syncthreads();
    int n = min(wpos, NCAND);
    if (tid == 0) ccnt[row] = n;
    if (tid < NCAND) {
        cval[(size_t)row * NCAND + tid] = (tid < n) ? scv[tid] : -1e30f;
        cidx[(size_t)row * NCAND + tid] = (tid < n) ? sci[tid] : -1;
    }
}

// ---------------------------------------------------------------------------
// Exact top-32, sort-free (replaces the two bitonic256 sorts):
//   rank-by-count on (val desc, idx asc); a32 = rank-31 approx value;
//   certain-in (> a32+DZ) keep approx at slot=rank; zone [a32-DZ, a32+DZ]
//   recomputed exactly (f32 wave dots), re-ranked by exact among zone.
// ---------------------------------------------------------------------------
__global__ __launch_bounds__(256) void fix_topk(
    const float* __restrict__ x, const float* __restrict__ b_pre,
    const float* __restrict__ W, const float* __restrict__ b_act,
    const float* __restrict__ cval, const int* __restrict__ cidx,
    float* __restrict__ sparse, float* __restrict__ vals, int* __restrict__ inds)
{
    const int row = blockIdx.x;
    const int tid = threadIdx.x;
    const int wid = tid >> 6, lane = tid & 63;

    __shared__ float xs[DM];
    for (int i = tid; i < DM; i += 256)
        xs[i] = x[(size_t)row * DM + i] - b_pre[i];

    __shared__ float sv[NCAND];
    __shared__ float sex[NCAND];
    __shared__ int   si[NCAND];
    __shared__ int   zlist[NCAND];
    __shared__ unsigned char zf[NCAND];
    __shared__ float sa32;
    __shared__ int   scin, zn;

    const float v  = cval[(size_t)row * NCAND + tid];   // -1e30 padding
    const int   id = cidx[(size_t)row * NCAND + tid];   // -1 padding
    sv[tid] = v; si[tid] = id; sex[tid] = v;
    if (tid == 0) { scin = 0; zn = 0; }
    if (tid < KTOP) {   // degenerate-row insurance
        vals[(size_t)row * KTOP + tid] = 0.f;
        inds[(size_t)row * KTOP + tid] = -1;
    }
    __syncthreads();

    // rank by count: val desc, idx asc tiebreak (LDS broadcast reads)
    int rank = 0;
    for (int j = 0; j < NCAND; ++j) {
        float ov = sv[j];
        rank += (ov > v) || (ov == v && si[j] < id);
    }
    if (rank == 31) sa32 = v;
    __syncthreads();

    const float a32 = sa32;
    const bool cin  = v > a32 + DZ;
    const bool zone = !cin && (v >= a32 - DZ) && (id >= 0);

    unsigned long long bal = __ballot(cin);
    if (lane == 0) atomicAdd(&scin, (int)__popcll(bal));
    if (zone) { int p = atomicAdd(&zn, 1); zlist[p] = tid; }
    zf[tid] = zone ? 1 : 0;
    __syncthreads();

    const int cin_total = scin;     // <= 31 by construction
    const int znum = zn;            // >= 32 - cin_total by construction

    // exact f32 recompute of zone members, one per wave (W rows L3-resident)
    for (int m = wid; m < znum; m += 4) {
        int t = zlist[m];
        int h = si[t];
        const float* wrow = W + (size_t)h * DM;
        float s = 0.f;
        #pragma unroll
        for (int c = 0; c < 16; ++c)
            s = fmaf(xs[lane + c * 64], wrow[lane + c * 64], s);
        #pragma unroll
        for (int off = 32; off; off >>= 1) s += __shfl_down(s, off);
        if (lane == 0) sex[t] = s + b_act[h];
    }
    __syncthreads();

    int slot = -1;
    float outv = 0.f;
    if (cin) { slot = rank; outv = v; }
    else if (zone) {
        float ev = sex[tid];
        int zrank = 0;
        for (int j = 0; j < NCAND; ++j) {
            if (zf[j]) {
                float ov = sex[j];
                zrank += (ov > ev) || (ov == ev && si[j] < id);
            }
        }
        if (zrank < KTOP - cin_total) { slot = cin_total + zrank; outv = ev; }
    }
    if (slot >= 0) {
        float r = fmaxf(outv, 0.f);
        vals[(size_t)row * KTOP + slot] = r;
        inds[(size_t)row * KTOP + slot] = id;
        sparse[(size_t)row * DH + id] = r;
    }
}

// ---------------------------------------------------------------------------
// Transpose W_dec [DM, DH] f32 -> W_dec^T [DH, DM] bf16
// ---------------------------------------------------------------------------
__global__ __launch_bounds__(256) void transpose_dec(
    const float* __restrict__ W, ushort* __restrict__ WT)
{
    __shared__ float t[32][33];
    const int tx = threadIdx.x;   // 0..31
    const int ty = threadIdx.y;   // 0..7
    const int h0 = blockIdx.x * 32;
    const int d0 = blockIdx.y * 32;
    #pragma unroll
    for (int r = 0; r < 4; ++r)
        t[ty + r * 8][tx] = W[(size_t)(d0 + ty + r * 8) * DH + h0 + tx];
    __syncthreads();
    #pragma unroll
    for (int r = 0; r < 4; ++r)
        WT[(size_t)(h0 + ty + r * 8) * DM + d0 + tx] = f2bf(t[tx][ty + r * 8]);
}

// ---------------------------------------------------------------------------
// Decode: recon[n][d] = sum_j vals[n][j] * WdecT[inds[n][j]][d] + b_pre[d]
// ---------------------------------------------------------------------------
__global__ __launch_bounds__(256) void recon_kernel(
    const float* __restrict__ vals, const int* __restrict__ inds,
    const ushort* __restrict__ wdecT, const float* __restrict__ b_pre,
    float* __restrict__ recon)
{
    const int row = blockIdx.x;
    const int tid = threadIdx.x;
    __shared__ float lval[KTOP];
    __shared__ int   lind[KTOP];
    if (tid < KTOP) {
        lval[tid] = vals[(size_t)row * KTOP + tid];
        lind[tid] = inds[(size_t)row * KTOP + tid];
    }
    __syncthreads();

    const int d = tid * 4;
    float4 a = *(const float4*)&b_pre[d];
    #pragma unroll 8
    for (int j = 0; j < KTOP; ++j) {
        float vj = lval[j];
        int h = lind[j];
        if (vj != 0.f && h >= 0) {
            ushort4 w = *(const ushort4*)&wdecT[(size_t)h * DM + d];
            a.x = fmaf(vj, bf2f(w.x), a.x);
            a.y = fmaf(vj, bf2f(w.y), a.y);
            a.z = fmaf(vj, bf2f(w.z), a.z);
            a.w = fmaf(vj, bf2f(w.w), a.w);
        }
    }
    *(float4*)&recon[(size_t)row * DM + d] = a;
}

// ---------------------------------------------------------------------------
extern "C" void kernel_launch(void* const* d_in, const int* in_sizes, int n_in,
                              void* d_out, int out_size, void* d_ws, size_t ws_size,
                              hipStream_t stream)
{
    const float* x     = (const float*)d_in[0];
    const float* W_enc = (const float*)d_in[1];
    const float* W_dec = (const float*)d_in[2];
    const float* b_pre = (const float*)d_in[3];
    const float* b_act = (const float*)d_in[4];

    float* recon  = (float*)d_out;                       // [N, DM]
    float* sparse = recon + (size_t)N_TOK * DM;          // [N, DH]
    float* pre    = sparse + (size_t)N_TOK * DH;         // [N, DH]

    // bf16 staging of A/B inside the sparse output region (zeroed later by
    // topk_cand, which runs after gemm has consumed them)
    ushort* Abf = (ushort*)sparse;                       // 16.8 MB
    ushort* Bbf = Abf + (size_t)N_TOK * DM;              // 33.5 MB

    // workspace (~52.5 MB, proven footprint)
    float*  cval  = (float*)d_ws;                               // 8.39 MB
    int*    cidx  = (int*)(cval + (size_t)N_TOK * NCAND);       // 8.39 MB
    int*    ccnt  = cidx + (size_t)N_TOK * NCAND;               // 32 KB
    float*  vals  = (float*)(ccnt + N_TOK);                     // 1.05 MB
    int*    inds  = (int*)(vals + (size_t)N_TOK * KTOP);        // 1.05 MB
    ushort* wdecT = (ushort*)(inds + (size_t)N_TOK * KTOP);     // 33.5 MB

    conv_x<<<N_TOK * DM / 1024, 256, 0, stream>>>(x, b_pre, Abf);
    conv_w<<<DH * DM / 1024, 256, 0, stream>>>(W_enc, Bbf);

    gemm_bf16<<<(N_TOK / 128) * (DH / 128), 256, 0, stream>>>(Abf, Bbf, b_act, pre);

    transpose_dec<<<dim3(DH / 32, DM / 32), dim3(32, 8), 0, stream>>>(W_dec, wdecT);

    topk_cand<<<N_TOK, 512, 0, stream>>>(pre, sparse, cval, cidx, ccnt);

    fix_topk<<<N_TOK, 256, 0, stream>>>(x, b_pre, W_enc, b_act,
                                        cval, cidx, sparse, vals, inds);

    recon_kernel<<<N_TOK, 256, 0, stream>>>(vals, inds, wdecT, b_pre, recon);
}